// Round 9
// baseline (28288.098 us; speedup 1.0000x reference)
//
#include <hip/hip_runtime.h>

// 3-layer LSTM encoder. B=512, T=512, F=8, HID=128, EMB=64.
// Pipelined mega-kernel: 96 blocks = 3 stages x 32 batch-tiles.
// R9: (1) 4-chunk RING handoff per tile (64KB slots; stays L2/L3-resident)
//     with producer backpressure flags -> no HBM round trip;
//     (2) 2-step-ahead x prefetch (parity register pairs) -> no per-step
//     vmcnt stall. Keeps R8: x-MFMA in trans shadow, bias-folded acc init,
//     lgkmcnt-only in-loop barrier.
// ws: [ring1 8MB][ring2 8MB][flags 128 ints]

#define DEVI __device__ __forceinline__

typedef _Float16 h8 __attribute__((ext_vector_type(8)));
typedef float f4 __attribute__((ext_vector_type(4)));

static constexpr int T_ = 512, TC_ = 16, NC_ = T_ / TC_, RC_ = 4;

DEVI float sigmoidf_(float x) {
    return __builtin_amdgcn_rcpf(1.f + __builtin_amdgcn_exp2f(x * -1.44269504f));
}
DEVI float tanhf_(float x) {
    return 2.f * __builtin_amdgcn_rcpf(1.f + __builtin_amdgcn_exp2f(x * -2.88539008f)) - 1.f;
}

DEVI h8 cvt8(const float* p) {
    const float4 a = *reinterpret_cast<const float4*>(p);
    const float4 b = *reinterpret_cast<const float4*>(p + 4);
    return h8{(_Float16)a.x, (_Float16)a.y, (_Float16)a.z, (_Float16)a.w,
              (_Float16)b.x, (_Float16)b.y, (_Float16)b.z, (_Float16)b.w};
}

// LDS-only barrier: orders h_lds writes/reads without draining vmcnt.
DEVI void lds_barrier() {
    asm volatile("s_waitcnt lgkmcnt(0)\n\ts_barrier" ::: "memory");
}

// ring element: [tile][slot(4)][tt(16)][row(16)][col(128)] f16
DEVI size_t ring_off(int tile, int t, int row, int col) {
    return ((((size_t)tile * RC_ + ((t >> 4) & (RC_ - 1))) * TC_ + (t & (TC_ - 1))) * 16 + row) * 128 + col;
}

// LAYER=1: H=128, x from f32 input (K=8 zero-padded), producer only
// LAYER=2: H=128, x from ring1, writes ring2, consumer+producer
// LAYER=3: H=64,  x from ring2, writes out (t=511), consumer only
template <int LAYER>
DEVI void stage(int tile, char* smem, const float* x, const _Float16* rin,
                _Float16* rout, const float* Wih, const float* Whh,
                const float* bih, const float* bhh, float* out,
                int* p_in, int* c_in, int* p_out, int* c_out) {
    constexpr int H = (LAYER == 3) ? 64 : 128;
    constexpr int KT_H = H / 32;               // K-tiles for h@Whh
    constexpr int KT_X = (LAYER == 1) ? 1 : 4; // K-tiles for x@Wih
    constexpr int HP = H + 8;                  // padded LDS row (f16)
    constexpr int NWAVE = (LAYER == 3) ? 4 : 8;

    const int tid  = threadIdx.x;
    const int lane = tid & 63;
    const int wv   = tid >> 6;
    const int lr   = lane & 15;       // fragment row (batch) / col (j)
    const int lk   = lane >> 4;       // k-group 0..3
    const int b0   = tile * 16;
    const bool active = (wv < NWAVE);
    const int jcol = (wv & (NWAVE - 1)) * 16 + lr;

    _Float16 (*h_lds)[16][HP] = (_Float16 (*)[16][HP])smem;

    // ---- resident weight B-frags (f32 -> f16 once) ----
    h8 wbh[4][KT_H], wbx[4][KT_X];
    float bias[4];
    if (active) {
#pragma unroll
        for (int q = 0; q < 4; q++) {
#pragma unroll
            for (int kt = 0; kt < KT_H; kt++)
                wbh[q][kt] = cvt8(Whh + (size_t)(q * H + jcol) * H + kt * 32 + lk * 8);
            if constexpr (LAYER == 1) {
                wbx[q][0] = (lk == 0) ? cvt8(Wih + (size_t)(q * H + jcol) * 8) : h8{};
            } else {
#pragma unroll
                for (int kt = 0; kt < KT_X; kt++)
                    wbx[q][kt] = cvt8(Wih + (size_t)(q * H + jcol) * 128 + kt * 32 + lk * 8);
            }
            bias[q] = bih[q * H + jcol] + bhh[q * H + jcol];
        }
    }

    float c[4] = {0.f, 0.f, 0.f, 0.f};

    for (int i = tid; i < 2 * 16 * HP; i += 512) ((_Float16*)smem)[i] = (_Float16)0;
    __syncthreads();

    auto load_x = [&](int t, h8* xa) {
        if constexpr (LAYER == 1) {
            xa[0] = (lk == 0) ? cvt8(x + ((size_t)(b0 + lr) * T_ + t) * 8) : h8{};
        } else {
            const size_t base = ring_off(tile, t, lr, 0);
#pragma unroll
            for (int kt = 0; kt < KT_X; kt++)
                xa[kt] = *reinterpret_cast<const h8*>(rin + base + kt * 32 + lk * 8);
        }
    };

    // accx = bias + x_t @ Wih^T  (bias folded into accumulator init)
    auto xmfma = [&](const h8* xv, f4* ax) {
#pragma unroll
        for (int q = 0; q < 4; q++) ax[q] = f4{bias[q], bias[q], bias[q], bias[q]};
#pragma unroll
        for (int kt = 0; kt < KT_X; kt++)
#pragma unroll
            for (int q = 0; q < 4; q++)
                ax[q] = __builtin_amdgcn_mfma_f32_16x16x32_f16(xv[kt], wbx[q][kt], ax[q], 0, 0, 0);
    };

    h8 xs[2][KT_X];     // parity-rotated prefetch slots: xs[t&1] holds x(t)
    f4 accx[4];

    for (int ch = 0; ch < NC_; ch++) {
        // ---- chunk-head sync: data-ready (consumer) + backpressure (producer) ----
        if (tid == 0) {
            if constexpr (LAYER > 1) {   // wait for input chunk ch
                while (__hip_atomic_load(p_in, __ATOMIC_RELAXED,
                                         __HIP_MEMORY_SCOPE_AGENT) < ch + 1)
                    __builtin_amdgcn_s_sleep(2);
            }
            if constexpr (LAYER < 3) {   // wait for output ring slot free
                while (__hip_atomic_load(c_out, __ATOMIC_RELAXED,
                                         __HIP_MEMORY_SCOPE_AGENT) < ch - (RC_ - 1))
                    __builtin_amdgcn_s_sleep(2);
            }
            __threadfence();   // acquire: invalidate stale cached ring lines
        }
        __syncthreads();

        if (active) {
            load_x(ch * TC_, xs[0]);
            load_x(ch * TC_ + 1, xs[1]);
            xmfma(xs[0], accx);          // chunk-head projection (unshadowed)
        }

        for (int tt = 0; tt < TC_; tt++) {
            const int t = ch * TC_ + tt;
            const int cur = t & 1;
            if (active) {
                // h ds_read first: latency overlaps acc copy
                h8 ha[KT_H];
#pragma unroll
                for (int kt = 0; kt < KT_H; kt++)
                    ha[kt] = *reinterpret_cast<const h8*>(&h_lds[cur][lr][kt * 32 + lk * 8]);

                f4 acc[4];
#pragma unroll
                for (int q = 0; q < 4; q++) acc[q] = accx[q];

                // h @ Whh^T — the only matmul on the recurrent critical path
#pragma unroll
                for (int kt = 0; kt < KT_H; kt++)
#pragma unroll
                    for (int q = 0; q < 4; q++)
                        acc[q] = __builtin_amdgcn_mfma_f32_16x16x32_f16(ha[kt], wbh[q][kt], acc[q], 0, 0, 0);

                // prefetch x(t+2) into the slot freed at end of step t-1
                if (tt + 2 < TC_) load_x(t + 2, xs[tt & 1]);

                // pointwise LSTM cell update: rows lk*4+i, col jcol
#pragma unroll
                for (int i = 0; i < 4; i++) {
                    const float gi = sigmoidf_(acc[0][i]);
                    const float gf = sigmoidf_(acc[1][i]);
                    const float gg = tanhf_(acc[2][i]);
                    const float go = sigmoidf_(acc[3][i]);
                    c[i] = gf * c[i] + gi * gg;
                    const float h = go * tanhf_(c[i]);
                    const int row = lk * 4 + i;
                    h_lds[cur ^ 1][row][jcol] = (_Float16)h;
                    if constexpr (LAYER < 3) {
                        rout[ring_off(tile, t, row, jcol)] = (_Float16)h;
                    } else {
                        if (t == T_ - 1) out[(size_t)(b0 + row) * 64 + jcol] = h;
                    }
                }

                // next step's x-projection in the trans-phase shadow
                // (consumes xs[(tt+1)&1], loaded ~1.7 steps ago)
                if (tt + 1 < TC_) xmfma(xs[(tt + 1) & 1], accx);
            }
            lds_barrier();   // LDS-only ordering: global ops keep flying
        }

        // ---- chunk-end publishes ----
        if constexpr (LAYER < 3) {
            asm volatile("s_waitcnt vmcnt(0)" ::: "memory");  // drain ring stores
        }
        __syncthreads();
        if (tid == 0) {
            if constexpr (LAYER < 3) {
                __threadfence();   // release: ring data visible at coherent point
                __hip_atomic_store(p_out, ch + 1, __ATOMIC_RELAXED,
                                   __HIP_MEMORY_SCOPE_AGENT);
            }
            if constexpr (LAYER > 1) {  // all reads of input chunk ch complete
                __hip_atomic_store(c_in, ch + 1, __ATOMIC_RELAXED,
                                   __HIP_MEMORY_SCOPE_AGENT);
            }
        }
    }
}

__global__ __launch_bounds__(512, 1)
void mega_k(const float* __restrict__ x,
            const float* __restrict__ Wih1, const float* __restrict__ Whh1,
            const float* __restrict__ bih1, const float* __restrict__ bhh1,
            const float* __restrict__ Wih2, const float* __restrict__ Whh2,
            const float* __restrict__ bih2, const float* __restrict__ bhh2,
            const float* __restrict__ Wih3, const float* __restrict__ Whh3,
            const float* __restrict__ bih3, const float* __restrict__ bhh3,
            _Float16* __restrict__ ring1, _Float16* __restrict__ ring2,
            float* __restrict__ out, int* __restrict__ flags) {
    extern __shared__ char smem[];
    const int bid = blockIdx.x;
    int* prod1 = flags;        // [32]
    int* prod2 = flags + 32;   // [32]
    int* cons1 = flags + 64;   // [32]
    int* cons2 = flags + 96;   // [32]
    if (bid < 32) {
        stage<1>(bid, smem, x, nullptr, ring1, Wih1, Whh1, bih1, bhh1, nullptr,
                 nullptr, nullptr, prod1 + bid, cons1 + bid);
    } else if (bid < 64) {
        const int t = bid - 32;
        stage<2>(t, smem, nullptr, ring1, ring2, Wih2, Whh2, bih2, bhh2, nullptr,
                 prod1 + t, cons1 + t, prod2 + t, cons2 + t);
    } else {
        const int t = bid - 64;
        stage<3>(t, smem, nullptr, ring2, nullptr, Wih3, Whh3, bih3, bhh3, out,
                 prod2 + t, cons2 + t, nullptr, nullptr);
    }
}

__global__ void zero_flags_k(int* flags) {
    if (threadIdx.x < 128)
        __hip_atomic_store(flags + threadIdx.x, 0, __ATOMIC_RELAXED,
                           __HIP_MEMORY_SCOPE_AGENT);
}

extern "C" void kernel_launch(void* const* d_in, const int* in_sizes, int n_in,
                              void* d_out, int out_size, void* d_ws, size_t ws_size,
                              hipStream_t stream) {
    const float* x = (const float*)d_in[0];
    float* out = (float*)d_out;

    char* ws = (char*)d_ws;
    // ring: 32 tiles * 4 slots * 16 tt * 16 rows * 128 cols * 2B = 8,388,608 B
    _Float16* ring1 = (_Float16*)ws;
    _Float16* ring2 = (_Float16*)(ws + (size_t)8388608);
    int* flags      = (int*)(ws + (size_t)16777216);
    (void)ws_size; (void)in_sizes; (void)n_in; (void)out_size;

    zero_flags_k<<<1, 128, 0, stream>>>(flags);
    mega_k<<<96, 512, 8704, stream>>>(
        x,
        (const float*)d_in[1], (const float*)d_in[2], (const float*)d_in[3], (const float*)d_in[4],
        (const float*)d_in[5], (const float*)d_in[6], (const float*)d_in[7], (const float*)d_in[8],
        (const float*)d_in[9], (const float*)d_in[10], (const float*)d_in[11], (const float*)d_in[12],
        ring1, ring2, out, flags);
}

// Round 10
// 723.420 us; speedup vs baseline: 39.1033x; 39.1033x over previous
//
#include <hip/hip_runtime.h>

// 3-layer LSTM encoder. B=512, T=512, F=8, HID=128, EMB=64.
// Pipelined mega-kernel: 96 blocks = 3 stages x 32 batch-tiles (R8 structure,
// ring reverted). R10: 2-step-ahead x prefetch + acc ping-pong, both with
// compile-time register slots via 2x-unrolled step bodies (even/odd).
// x@Wih MFMA runs in the trans shadow of the PREVIOUS step; bias folded into
// acc init; in-loop barrier is lgkmcnt-only. ws: [O1 67MB][O2 67MB][flags]

#define DEVI __device__ __forceinline__

typedef _Float16 h8 __attribute__((ext_vector_type(8)));
typedef float f4 __attribute__((ext_vector_type(4)));

static constexpr int T_ = 512, TC_ = 16, NC_ = T_ / TC_;

DEVI float sigmoidf_(float x) {
    return __builtin_amdgcn_rcpf(1.f + __builtin_amdgcn_exp2f(x * -1.44269504f));
}
DEVI float tanhf_(float x) {
    return 2.f * __builtin_amdgcn_rcpf(1.f + __builtin_amdgcn_exp2f(x * -2.88539008f)) - 1.f;
}

DEVI h8 cvt8(const float* p) {
    const float4 a = *reinterpret_cast<const float4*>(p);
    const float4 b = *reinterpret_cast<const float4*>(p + 4);
    return h8{(_Float16)a.x, (_Float16)a.y, (_Float16)a.z, (_Float16)a.w,
              (_Float16)b.x, (_Float16)b.y, (_Float16)b.z, (_Float16)b.w};
}

// LDS-only barrier: orders h_lds writes/reads without draining vmcnt.
DEVI void lds_barrier() {
    asm volatile("s_waitcnt lgkmcnt(0)\n\ts_barrier" ::: "memory");
}

// LAYER=1: H=128, x from f32 input (K=8 zero-padded), producer only
// LAYER=2: H=128, x from O1, writes O2, consumer+producer
// LAYER=3: H=64,  x from O2, writes out (t=511), consumer only
template <int LAYER>
DEVI void stage(int tile, char* smem, const float* x, const _Float16* Oin,
                _Float16* Oout, const float* Wih, const float* Whh,
                const float* bih, const float* bhh, float* out,
                int* flag_in, int* flag_out) {
    constexpr int H = (LAYER == 3) ? 64 : 128;
    constexpr int KT_H = H / 32;               // K-tiles for h@Whh
    constexpr int KT_X = (LAYER == 1) ? 1 : 4; // K-tiles for x@Wih
    constexpr int HP = H + 8;                  // padded LDS row (f16)
    constexpr int NWAVE = (LAYER == 3) ? 4 : 8;

    const int tid  = threadIdx.x;
    const int lane = tid & 63;
    const int wv   = tid >> 6;
    const int lr   = lane & 15;       // fragment row (batch) / col (j)
    const int lk   = lane >> 4;       // k-group 0..3
    const int b0   = tile * 16;
    const bool active = (wv < NWAVE);
    const int jcol = (wv & (NWAVE - 1)) * 16 + lr;

    _Float16 (*h_lds)[16][HP] = (_Float16 (*)[16][HP])smem;

    // ---- resident weight B-frags (f32 -> f16 once) ----
    h8 wbh[4][KT_H], wbx[4][KT_X];
    float bias[4];
    if (active) {
#pragma unroll
        for (int q = 0; q < 4; q++) {
#pragma unroll
            for (int kt = 0; kt < KT_H; kt++)
                wbh[q][kt] = cvt8(Whh + (size_t)(q * H + jcol) * H + kt * 32 + lk * 8);
            if constexpr (LAYER == 1) {
                wbx[q][0] = (lk == 0) ? cvt8(Wih + (size_t)(q * H + jcol) * 8) : h8{};
            } else {
#pragma unroll
                for (int kt = 0; kt < KT_X; kt++)
                    wbx[q][kt] = cvt8(Wih + (size_t)(q * H + jcol) * 128 + kt * 32 + lk * 8);
            }
            bias[q] = bih[q * H + jcol] + bhh[q * H + jcol];
        }
    }

    float c[4] = {0.f, 0.f, 0.f, 0.f};

    for (int i = tid; i < 2 * 16 * HP; i += 512) ((_Float16*)smem)[i] = (_Float16)0;
    __syncthreads();

    auto load_x = [&](int t, h8* xa) {
        if constexpr (LAYER == 1) {
            xa[0] = (lk == 0) ? cvt8(x + ((size_t)(b0 + lr) * T_ + t) * 8) : h8{};
        } else {
#pragma unroll
            for (int kt = 0; kt < KT_X; kt++)
                xa[kt] = *reinterpret_cast<const h8*>(
                    Oin + ((size_t)(b0 + lr) * T_ + t) * 128 + kt * 32 + lk * 8);
        }
    };

    // ax = bias + x @ Wih^T  (bias folded into accumulator init)
    auto xmfma = [&](const h8* xv, f4* ax) {
#pragma unroll
        for (int q = 0; q < 4; q++) ax[q] = f4{bias[q], bias[q], bias[q], bias[q]};
#pragma unroll
        for (int kt = 0; kt < KT_X; kt++)
#pragma unroll
            for (int q = 0; q < 4; q++)
                ax[q] = __builtin_amdgcn_mfma_f32_16x16x32_f16(xv[kt], wbx[q][kt], ax[q], 0, 0, 0);
    };

    h8 xa[KT_X], xb[KT_X];    // static 2-slot prefetch: xa=even-step x, xb=odd
    f4 accA[4], accB[4];      // static acc ping-pong

    // one step; all slot choices compile-time via macro args
#define STEP_BODY(T_EXPR, TT, CUR, ACCU, ACCN, XLOAD, XPROJ)                              \
    {                                                                                     \
        const int t = (T_EXPR);                                                           \
        h8 ha[KT_H];                                                                      \
        _Pragma("unroll")                                                                 \
        for (int kt = 0; kt < KT_H; kt++)                                                 \
            ha[kt] = *reinterpret_cast<const h8*>(&h_lds[CUR][lr][kt * 32 + lk * 8]);     \
        _Pragma("unroll")                                                                 \
        for (int kt = 0; kt < KT_H; kt++)                                                 \
            _Pragma("unroll")                                                             \
            for (int q = 0; q < 4; q++)                                                   \
                ACCU[q] = __builtin_amdgcn_mfma_f32_16x16x32_f16(ha[kt], wbh[q][kt],      \
                                                                 ACCU[q], 0, 0, 0);       \
        if ((TT) + 2 < TC_) load_x(t + 2, XLOAD);  /* consumed end of NEXT step */        \
        _Pragma("unroll")                                                                 \
        for (int i = 0; i < 4; i++) {                                                     \
            const float gi = sigmoidf_(ACCU[0][i]);                                       \
            const float gf = sigmoidf_(ACCU[1][i]);                                       \
            const float gg = tanhf_(ACCU[2][i]);                                          \
            const float go = sigmoidf_(ACCU[3][i]);                                       \
            c[i] = gf * c[i] + gi * gg;                                                   \
            const float h = go * tanhf_(c[i]);                                            \
            const int row = lk * 4 + i;                                                   \
            h_lds[(CUR) ^ 1][row][jcol] = (_Float16)h;                                    \
            if constexpr (LAYER < 3) {                                                    \
                Oout[((size_t)(b0 + row) * T_ + t) * 128 + jcol] = (_Float16)h;           \
            } else {                                                                      \
                if (t == T_ - 1) out[(size_t)(b0 + row) * 64 + jcol] = h;                 \
            }                                                                             \
        }                                                                                 \
        if ((TT) + 1 < TC_) xmfma(XPROJ, ACCN);  /* next step's x-proj in trans shadow */ \
    }

    for (int ch = 0; ch < NC_; ch++) {
        // ---- consumer: wait for input chunk ch ----
        if constexpr (LAYER > 1) {
            if (tid == 0) {
                while (__hip_atomic_load(flag_in, __ATOMIC_RELAXED,
                                         __HIP_MEMORY_SCOPE_AGENT) < ch + 1)
                    __builtin_amdgcn_s_sleep(2);
                __threadfence();   // agent acquire: inv caches before data reads
            }
            __syncthreads();
        }
        const int t0 = ch * TC_;
        if (active) {
            load_x(t0, xa);
            load_x(t0 + 1, xb);
            xmfma(xa, accA);       // chunk-head projection (unshadowed, 1/16 steps)
        }

        for (int tb = 0; tb < TC_ / 2; tb++) {
            // even step: reads h_lds[0] -> writes h_lds[1]
            if (active) STEP_BODY(t0 + 2 * tb, 2 * tb, 0, accA, accB, xa, xb);
            lds_barrier();
            // odd step: reads h_lds[1] -> writes h_lds[0]
            if (active) STEP_BODY(t0 + 2 * tb + 1, 2 * tb + 1, 1, accB, accA, xb, xa);
            lds_barrier();
        }

        // ---- producer: publish chunk ch (drain own stores first) ----
        if constexpr (LAYER < 3) {
            asm volatile("s_waitcnt vmcnt(0)" ::: "memory");
            __syncthreads();
            if (tid == 0) {
                __threadfence();   // agent release: visible at coherent point
                __hip_atomic_store(flag_out, ch + 1, __ATOMIC_RELAXED,
                                   __HIP_MEMORY_SCOPE_AGENT);
            }
        }
    }
#undef STEP_BODY
}

__global__ __launch_bounds__(512, 1)
void mega_k(const float* __restrict__ x,
            const float* __restrict__ Wih1, const float* __restrict__ Whh1,
            const float* __restrict__ bih1, const float* __restrict__ bhh1,
            const float* __restrict__ Wih2, const float* __restrict__ Whh2,
            const float* __restrict__ bih2, const float* __restrict__ bhh2,
            const float* __restrict__ Wih3, const float* __restrict__ Whh3,
            const float* __restrict__ bih3, const float* __restrict__ bhh3,
            _Float16* __restrict__ O1, _Float16* __restrict__ O2,
            float* __restrict__ out, int* __restrict__ flags) {
    extern __shared__ char smem[];
    const int bid = blockIdx.x;
    if (bid < 32) {
        stage<1>(bid, smem, x, nullptr, O1, Wih1, Whh1, bih1, bhh1, nullptr,
                 nullptr, flags + bid);
    } else if (bid < 64) {
        stage<2>(bid - 32, smem, nullptr, O1, O2, Wih2, Whh2, bih2, bhh2, nullptr,
                 flags + (bid - 32), flags + 32 + (bid - 32));
    } else {
        stage<3>(bid - 64, smem, nullptr, O2, nullptr, Wih3, Whh3, bih3, bhh3, out,
                 flags + 32 + (bid - 64), nullptr);
    }
}

__global__ void zero_flags_k(int* flags) {
    if (threadIdx.x < 64)
        __hip_atomic_store(flags + threadIdx.x, 0, __ATOMIC_RELAXED,
                           __HIP_MEMORY_SCOPE_AGENT);
}

extern "C" void kernel_launch(void* const* d_in, const int* in_sizes, int n_in,
                              void* d_out, int out_size, void* d_ws, size_t ws_size,
                              hipStream_t stream) {
    const float* x = (const float*)d_in[0];
    float* out = (float*)d_out;

    char* ws = (char*)d_ws;
    _Float16* O1 = (_Float16*)ws;                         // 67,108,864 B
    _Float16* O2 = (_Float16*)(ws + (size_t)67108864);    // 67,108,864 B
    int* flags   = (int*)(ws + (size_t)134217728);        // 256 B
    (void)ws_size; (void)in_sizes; (void)n_in; (void)out_size;

    zero_flags_k<<<1, 64, 0, stream>>>(flags);
    mega_k<<<96, 512, 8704, stream>>>(
        x,
        (const float*)d_in[1], (const float*)d_in[2], (const float*)d_in[3], (const float*)d_in[4],
        (const float*)d_in[5], (const float*)d_in[6], (const float*)d_in[7], (const float*)d_in[8],
        (const float*)d_in[9], (const float*)d_in[10], (const float*)d_in[11], (const float*)d_in[12],
        O1, O2, out, flags);
}